// Round 11
// baseline (897.919 us; speedup 1.0000x reference)
//
#include <hip/hip_runtime.h>
#include <stdint.h>
#include <math.h>

#define NTOK 65536
#define DIM  128
#define KC   1024
#define MARGIN 1e-2f

// ---------- Threefry-2x32-20, key=(0,42), partitionable: bits(j)=o0^o1 of
// cipher(x0=hi32(j)=0, x1=lo32(j)=j).  [CONFIRMED by round-8/9 pass] --------
static __device__ __forceinline__ uint32_t tf_xor(uint32_t j) {
  const uint32_t K0 = 0u, K1 = 42u, K2 = 0x1BD11BDAu ^ K0 ^ K1;
  const uint32_t ks[3] = {K0, K1, K2};
  uint32_t x0 = K0;
  uint32_t x1 = j + K1;
#pragma unroll
  for (int i = 0; i < 5; ++i) {
    const int rA[4] = {13, 15, 26, 6};
    const int rB[4] = {17, 29, 16, 24};
#pragma unroll
    for (int r4 = 0; r4 < 4; ++r4) {
      const int r = (i & 1) ? rB[r4] : rA[r4];
      x0 += x1;
      x1 = (x1 << r) | (x1 >> (32 - r));
      x1 ^= x0;
    }
    x0 += ks[(i + 1) % 3];
    x1 += ks[(i + 2) % 3] + (uint32_t)(i + 1);
  }
  return x0 ^ x1;
}

// Fast screening gumbel: |error| <~ 2e-6 absolute on z (vs MARGIN 1e-2).
// Inner log: poly in exact dyadic delta for f>=0.75 (hardware log2 has
// absolute error near 1 -- and u~1 elements are the argmax winners).
static __device__ __forceinline__ float gumb_fast(uint32_t b) {
  float f = __uint_as_float((b >> 9) | 0x3f800000u) - 1.0f;  // [0,1) dyadic
  float w;
  if (f >= 0.75f) {
    float dd = 1.0f - f;               // exact
    float p = 0.1f;                    // -ln(1-d) = d*(1 + d/2 + ... + d^9/10)
    p = fmaf(p, dd, 0.11111111f);
    p = fmaf(p, dd, 0.125f);
    p = fmaf(p, dd, 0.14285714f);
    p = fmaf(p, dd, 0.16666667f);
    p = fmaf(p, dd, 0.2f);
    p = fmaf(p, dd, 0.25f);
    p = fmaf(p, dd, 0.33333333f);
    p = fmaf(p, dd, 0.5f);
    p = fmaf(p, dd, 1.0f);
    w = dd * p;
  } else {
    w = -__logf(fmaxf(f, 1.17549435e-38f));
  }
  return -__logf(w);
}

// Exact-decision gumbel (r8-identical): f64 logs, rounded to f32.
static __device__ __forceinline__ float gumb32(uint32_t b) {
  double f = (double)(b >> 9) * (1.0 / 8388608.0);
  const double tiny = 1.1754943508222875e-38;
  double u = (f > 0.0) ? f : tiny;
  return (float)(-log(-log(u)));
}

// ---------- codebook norms (f64) + EMA init + zero lpart/fix_count ---------
__global__ void vq_cnorm_ema(const float* __restrict__ cb, double* __restrict__ cnorm,
                             float* __restrict__ lpart, uint32_t* __restrict__ fix_count,
                             float* __restrict__ ncb) {
  const int k = blockIdx.x;
  const int t = threadIdx.x;  // 64
  float a = cb[k * DIM + t];
  float b = cb[k * DIM + 64 + t];
  ncb[k * DIM + t]      = 0.99f * a;
  ncb[k * DIM + 64 + t] = 0.99f * b;
  double da = (double)a, db = (double)b;
  double s = da * da + db * db;
#pragma unroll
  for (int off = 32; off >= 1; off >>= 1) s += __shfl_down(s, off, 64);
  if (t == 0) { cnorm[k] = s; lpart[k] = 0.0f; }
  if (k == 0 && t == 0) fix_count[0] = 0u;
}

// ---------- main: f32 screening argmax + top-2 margin flagging -------------
// 64 rows/block, 32-code tiles (LDS 51KB -> 3 blocks/CU).
// 256 threads = 16 row-groups x 16 code-groups; thread tile 4 rows x 2 codes.
__global__ __launch_bounds__(256, 3)
void vq_main(const float* __restrict__ x, const float* __restrict__ cb,
             const double* __restrict__ cnorm, uint32_t* __restrict__ out_idx,
             uint32_t* __restrict__ fix_count, uint32_t* __restrict__ fix_list) {
  __shared__ float xs[64 * 132];
  __shared__ float cs[32 * 132];
  __shared__ float xn_s[64];
  __shared__ float cn_s[32];

  const int tid = threadIdx.x;
  const int blk = blockIdx.x;
  const int rg = tid >> 4;
  const int cg = tid & 15;

  {
    const float4* xg = (const float4*)x;
#pragma unroll
    for (int q = 0; q < 8; ++q) {
      int li = tid + q * 256;          // 0..2047 (ALL 64 rows)
      int row = li >> 5, c4 = li & 31;
      *(float4*)(xs + row * 132 + c4 * 4) = xg[blk * 2048 + li];
    }
  }
  __syncthreads();
  if (tid < 64) {
    float s = 0.0f;
    const float* p = xs + tid * 132;
#pragma unroll
    for (int d = 0; d < DIM; ++d) s = fmaf(p[d], p[d], s);
    xn_s[tid] = s;
  }
  __syncthreads();

  const int r0 = 4 * rg;
  float xn[4] = {xn_s[r0], xn_s[r0 + 1], xn_s[r0 + 2], xn_s[r0 + 3]};
  const uint32_t R0g = (uint32_t)(blk * 64 + r0);
  const uint32_t jb[4] = {(R0g + 0u) << 10, (R0g + 1u) << 10,
                          (R0g + 2u) << 10, (R0g + 3u) << 10};

  float b1[4] = {-1e30f, -1e30f, -1e30f, -1e30f};
  float b2[4] = {-1e30f, -1e30f, -1e30f, -1e30f};
  int   k1[4] = {0, 0, 0, 0};

  const float* xp[4] = {xs + r0 * 132, xs + (r0 + 1) * 132,
                        xs + (r0 + 2) * 132, xs + (r0 + 3) * 132};
  const float* cp[2] = {cs + cg * 132, cs + (cg + 16) * 132};

  for (int kt = 0; kt < 32; ++kt) {
    {
      const float4* cg4 = (const float4*)cb;
#pragma unroll
      for (int q = 0; q < 4; ++q) {
        int li = tid + q * 256;        // 0..1023 (32 rows x 32 float4)
        int row = li >> 5, c4 = li & 31;
        *(float4*)(cs + row * 132 + c4 * 4) = cg4[kt * 1024 + li];
      }
      if (tid < 32) cn_s[tid] = (float)cnorm[kt * 32 + tid];
    }
    __syncthreads();

    float acc[4][2];
#pragma unroll
    for (int i = 0; i < 4; ++i)
#pragma unroll
      for (int j = 0; j < 2; ++j) acc[i][j] = 0.0f;

#pragma unroll 4
    for (int d = 0; d < DIM; d += 4) {
      float4 xv[4], cv[2];
#pragma unroll
      for (int i = 0; i < 4; ++i) xv[i] = *(const float4*)(xp[i] + d);
#pragma unroll
      for (int j = 0; j < 2; ++j) cv[j] = *(const float4*)(cp[j] + d);
#pragma unroll
      for (int i = 0; i < 4; ++i)
#pragma unroll
        for (int j = 0; j < 2; ++j) {
          acc[i][j] = fmaf(xv[i].x, cv[j].x, acc[i][j]);
          acc[i][j] = fmaf(xv[i].y, cv[j].y, acc[i][j]);
          acc[i][j] = fmaf(xv[i].z, cv[j].z, acc[i][j]);
          acc[i][j] = fmaf(xv[i].w, cv[j].w, acc[i][j]);
        }
    }

#pragma unroll
    for (int j = 0; j < 2; ++j) {
      const int kj = cg + 16 * j;
      const int kg = (kt << 5) + kj;
      const float cn = cn_s[kj];
#pragma unroll
      for (int i = 0; i < 4; ++i) {
        float g = gumb_fast(tf_xor(jb[i] + (uint32_t)kg));
        float d2 = (xn[i] + cn) - 2.0f * acc[i][j];
        float dist = sqrtf(fmaxf(d2, 1e-12f));
        float z = g - dist;
        if (z > b1[i]) { b2[i] = b1[i]; b1[i] = z; k1[i] = kg; }
        else if (z > b2[i]) b2[i] = z;
      }
    }
    __syncthreads();
  }

  // top-2 merge across the 16 code-group lanes (ties -> smaller k)
#pragma unroll
  for (int off = 8; off >= 1; off >>= 1) {
#pragma unroll
    for (int i = 0; i < 4; ++i) {
      float ov1 = __shfl_down(b1[i], off, 16);
      int   ok1 = __shfl_down(k1[i], off, 16);
      float ov2 = __shfl_down(b2[i], off, 16);
      if (ov1 > b1[i] || (ov1 == b1[i] && ok1 < k1[i])) {
        b2[i] = fmaxf(b1[i], ov2);
        b1[i] = ov1; k1[i] = ok1;
      } else {
        b2[i] = fmaxf(b2[i], ov1);
      }
    }
  }
  if (cg == 0) {
#pragma unroll
    for (int i = 0; i < 4; ++i) {
      out_idx[R0g + i] = (uint32_t)k1[i];
      if (b1[i] - b2[i] < MARGIN) {
        uint32_t pos = atomicAdd(fix_count, 1u);
        if (pos < NTOK) fix_list[pos] = R0g + i;
      }
    }
  }
}

// ---------- fixup: re-decide flagged rows with r8-identical arithmetic -----
__global__ __launch_bounds__(256)
void vq_fixup(const float* __restrict__ x, const float* __restrict__ cb,
              const double* __restrict__ cnorm, const uint32_t* __restrict__ fix_count,
              const uint32_t* __restrict__ fix_list, uint32_t* __restrict__ out_idx) {
  __shared__ float xrow[DIM];
  __shared__ double xn_sh;
  __shared__ double bz_sh[256];
  __shared__ int    bk_sh[256];

  const int t = threadIdx.x;  // 256
  const uint32_t cnt = fix_count[0];

  for (uint32_t e = blockIdx.x; e < cnt && e < NTOK; e += gridDim.x) {
    const uint32_t row = fix_list[e];
    if (t < 32) ((float4*)xrow)[t] = ((const float4*)(x + (size_t)row * DIM))[t];
    __syncthreads();
    if (t == 0) {
      double s = 0.0;
#pragma unroll
      for (int d = 0; d < DIM; ++d) s = fma((double)xrow[d], (double)xrow[d], s);
      xn_sh = s;
    }
    __syncthreads();
    const double xn = xn_sh;
    const uint32_t jb = row << 10;

    double bz = -1e300;
    int bk = 0;
#pragma unroll
    for (int q = 0; q < 4; ++q) {
      const int kg = t + q * 256;     // ascending per thread
      float acc = 0.0f;
      const float* crow = cb + (size_t)kg * DIM;
#pragma unroll
      for (int d = 0; d < DIM; ++d) acc = fmaf(xrow[d], crow[d], acc);
      float g = gumb32(tf_xor(jb + (uint32_t)kg));
      double d2 = (xn + cnorm[kg]) - 2.0 * (double)acc;
      double dist = sqrt(fmax(d2, 1e-12));
      double z = (double)g - dist;
      if (z > bz) { bz = z; bk = kg; }
    }
    bz_sh[t] = bz; bk_sh[t] = bk;
    __syncthreads();
    for (int s = 128; s >= 1; s >>= 1) {
      if (t < s) {
        double ov = bz_sh[t + s]; int ok = bk_sh[t + s];
        if (ov > bz_sh[t] || (ov == bz_sh[t] && ok < bk_sh[t])) {
          bz_sh[t] = ov; bk_sh[t] = ok;
        }
      }
      __syncthreads();
    }
    if (t == 0) out_idx[row] = (uint32_t)bk_sh[0];
    __syncthreads();
  }
}

// ---------- per-row finish: one wave per row -------------------------------
__global__ __launch_bounds__(256)
void vq_finish(const float* __restrict__ x, const float* __restrict__ cb,
               const uint32_t* __restrict__ idx, float* __restrict__ codes,
               float* __restrict__ ncb, float* __restrict__ lpart) {
  const int lane = threadIdx.x & 63;
  const int wid = threadIdx.x >> 6;

  for (int r = blockIdx.x * 4 + wid; r < NTOK; r += 8192) {
    const int k = (int)idx[r];
    float2 xv = ((const float2*)(x + (size_t)r * DIM))[lane];
    float2 cv = ((const float2*)(cb + (size_t)k * DIM))[lane];
    float dx = cv.x - xv.x, dy = cv.y - xv.y;
    float s = dx * dx + dy * dy;
#pragma unroll
    for (int off = 32; off >= 1; off >>= 1) s += __shfl_down(s, off, 64);

    atomicAdd(ncb + k * DIM + 2 * lane,     0.01f * xv.x);
    atomicAdd(ncb + k * DIM + 2 * lane + 1, 0.01f * xv.y);

    float4* crow = (float4*)(codes + (size_t)r * KC);
#pragma unroll
    for (int q = 0; q < 4; ++q) {
      int base = (lane * 4 + q) * 4;
      float4 v = make_float4(0.f, 0.f, 0.f, 0.f);
      int dlt = k - base;
      if (dlt >= 0 && dlt < 4) ((float*)&v)[dlt] = 1.0f;
      crow[lane * 4 + q] = v;
    }
    if (lane == 0) atomicAdd(lpart + (r & 1023), s);
  }
}

// ---------- loss = 1.25 * sum / (N*D) ----------
__global__ void vq_loss_final(const float* __restrict__ lpart, float* __restrict__ loss) {
  const int t = threadIdx.x;  // 256
  float s = 0.0f;
#pragma unroll
  for (int q = 0; q < 4; ++q) s += lpart[t + q * 256];
#pragma unroll
  for (int off = 32; off >= 1; off >>= 1) s += __shfl_down(s, off, 64);
  __shared__ float sw[4];
  if ((t & 63) == 0) sw[t >> 6] = s;
  __syncthreads();
  if (t == 0) {
    float total = (sw[0] + sw[1]) + (sw[2] + sw[3]);
    loss[0] = 1.25f * (total / 8388608.0f);
  }
}

extern "C" void kernel_launch(void* const* d_in, const int* in_sizes, int n_in,
                              void* d_out, int out_size, void* d_ws, size_t ws_size,
                              hipStream_t stream) {
  const float* x  = (const float*)d_in[0];   // (N, D) fp32
  const float* cb = (const float*)d_in[1];   // (K, D) fp32

  float* codes = (float*)d_out;                           // N*K f32
  float* loss  = (float*)d_out + (size_t)NTOK * KC;       // 1
  float* ncb   = loss + 1;                                // K*D

  uint32_t* idx       = (uint32_t*)d_ws;                          // 256 KB
  double*   cnorm     = (double*)(idx + NTOK);                    // 8 KB
  float*    lpart     = (float*)(cnorm + KC);                     // 4 KB
  uint32_t* fix_count = (uint32_t*)(lpart + KC);                  // 256 B
  uint32_t* fix_list  = fix_count + 64;                           // 256 KB

  vq_cnorm_ema<<<KC, 64, 0, stream>>>(cb, cnorm, lpart, fix_count, ncb);
  vq_main<<<1024, 256, 0, stream>>>(x, cb, cnorm, idx, fix_count, fix_list);
  vq_fixup<<<256, 256, 0, stream>>>(x, cb, cnorm, fix_count, fix_list, idx);
  vq_finish<<<2048, 256, 0, stream>>>(x, cb, idx, codes, ncb, lpart);
  vq_loss_final<<<1, 256, 0, stream>>>(lpart, loss);
}

// Round 13
// 701.398 us; speedup vs baseline: 1.2802x; 1.2802x over previous
//
#include <hip/hip_runtime.h>
#include <stdint.h>
#include <math.h>

#define NTOK 65536
#define DIM  128
#define KC   1024
#define MARGIN 1e-2f

typedef __attribute__((ext_vector_type(8))) short short8;
typedef __attribute__((ext_vector_type(4))) float f32x4;

// ---------- Threefry-2x32-20, key=(0,42), partitionable: bits(j)=o0^o1 of
// cipher(x0=hi32(j)=0, x1=lo32(j)=j).  [CONFIRMED r8/r9/r11] ----------------
static __device__ __forceinline__ uint32_t tf_xor(uint32_t j) {
  const uint32_t K0 = 0u, K1 = 42u, K2 = 0x1BD11BDAu ^ K0 ^ K1;
  const uint32_t ks[3] = {K0, K1, K2};
  uint32_t x0 = K0;
  uint32_t x1 = j + K1;
#pragma unroll
  for (int i = 0; i < 5; ++i) {
    const int rA[4] = {13, 15, 26, 6};
    const int rB[4] = {17, 29, 16, 24};
#pragma unroll
    for (int r4 = 0; r4 < 4; ++r4) {
      const int r = (i & 1) ? rB[r4] : rA[r4];
      x0 += x1;
      x1 = (x1 << r) | (x1 >> (32 - r));
      x1 ^= x0;
    }
    x0 += ks[(i + 1) % 3];
    x1 += ks[(i + 2) % 3] + (uint32_t)(i + 1);
  }
  return x0 ^ x1;
}

// Fast screening gumbel: |error| <~ 2e-6 on z (vs MARGIN 1e-2).
static __device__ __forceinline__ float gumb_fast(uint32_t b) {
  float f = __uint_as_float((b >> 9) | 0x3f800000u) - 1.0f;  // [0,1) dyadic
  float w;
  if (f >= 0.75f) {
    float dd = 1.0f - f;               // exact
    float p = 0.1f;
    p = fmaf(p, dd, 0.11111111f);
    p = fmaf(p, dd, 0.125f);
    p = fmaf(p, dd, 0.14285714f);
    p = fmaf(p, dd, 0.16666667f);
    p = fmaf(p, dd, 0.2f);
    p = fmaf(p, dd, 0.25f);
    p = fmaf(p, dd, 0.33333333f);
    p = fmaf(p, dd, 0.5f);
    p = fmaf(p, dd, 1.0f);
    w = dd * p;
  } else {
    w = -__logf(fmaxf(f, 1.17549435e-38f));
  }
  return -__logf(w);
}

// Exact-decision gumbel (r8-identical): f64 logs, rounded to f32.
static __device__ __forceinline__ float gumb32(uint32_t b) {
  double f = (double)(b >> 9) * (1.0 / 8388608.0);
  const double tiny = 1.1754943508222875e-38;
  double u = (f > 0.0) ? f : tiny;
  return (float)(-log(-log(u)));
}

// f32 -> bf16 RNE (bit ops; finite data only)
static __device__ __forceinline__ uint32_t f2bf(float v) {
  uint32_t u = __float_as_uint(v);
  return (u + 0x7FFFu + ((u >> 16) & 1u)) >> 16;
}
static __device__ __forceinline__ float bf2f(uint32_t b) {
  return __uint_as_float(b << 16);
}

// ---------- cnorms (f64+f32) + bf16 hi/lo codebook + EMA init + zeroing ----
__global__ void vq_cnorm_ema(const float* __restrict__ cb, double* __restrict__ cnorm,
                             float* __restrict__ cnf, ushort* __restrict__ cbhi,
                             ushort* __restrict__ cblo, float* __restrict__ lpart,
                             uint32_t* __restrict__ fix_count, float* __restrict__ ncb) {
  const int k = blockIdx.x;
  const int t = threadIdx.x;  // 64
  float a = cb[k * DIM + t];
  float b = cb[k * DIM + 64 + t];
  ncb[k * DIM + t]      = 0.99f * a;
  ncb[k * DIM + 64 + t] = 0.99f * b;
  uint32_t ah = f2bf(a), bh = f2bf(b);
  cbhi[k * DIM + t]      = (ushort)ah;
  cbhi[k * DIM + 64 + t] = (ushort)bh;
  cblo[k * DIM + t]      = (ushort)f2bf(a - bf2f(ah));
  cblo[k * DIM + 64 + t] = (ushort)f2bf(b - bf2f(bh));
  double da = (double)a, db = (double)b;
  double s = da * da + db * db;
#pragma unroll
  for (int off = 32; off >= 1; off >>= 1) s += __shfl_down(s, off, 64);
  if (t == 0) { cnorm[k] = s; cnf[k] = (float)s; lpart[k] = 0.0f; }
  if (k == 0 && t == 0) fix_count[0] = 0u;
}

// ---------- main: MFMA bf16x2 screen + top-2 margin flagging ---------------
// 1024 blocks x 256 thr (4 waves). Block = 64 rows; wave = 16 rows x all codes.
// Per wave, per 32-code tile: two 16x16 MFMA subtiles, K=128 via 4 steps,
// dot = hi*hi + hi*lo + lo*hi chained in one f32 accumulator.
__global__ __launch_bounds__(256, 3)
void vq_main(const float* __restrict__ x,
             const ushort* __restrict__ cbhi, const ushort* __restrict__ cblo,
             const float* __restrict__ cnf, uint32_t* __restrict__ out_idx,
             uint32_t* __restrict__ fix_count, uint32_t* __restrict__ fix_list) {
  __shared__ ushort csh[32 * 136];
  __shared__ ushort csl[32 * 136];
  __shared__ float cn_s[32];

  const int tid = threadIdx.x;
  const int wid = tid >> 6;
  const int l = tid & 63;
  const int blk = blockIdx.x;
  const int colc = l & 15;   // A-row class / B-col class / C-col
  const int kgrp = l >> 4;   // 0..3 (k-group of 8)

  // one-time: A fragments (this wave's 16 rows x 128 k) -> registers (bf16 hi/lo)
  const int arow_g = blk * 64 + wid * 16 + colc;
  short8 a_hi[4], a_lo[4];
  float xnpart = 0.0f;
  const float* xrow = x + (size_t)arow_g * DIM;
#pragma unroll
  for (int kk = 0; kk < 4; ++kk) {
    int k0 = kk * 32 + kgrp * 8;
    float4 p0 = *(const float4*)(xrow + k0);
    float4 p1 = *(const float4*)(xrow + k0 + 4);
    float vv[8] = {p0.x, p0.y, p0.z, p0.w, p1.x, p1.y, p1.z, p1.w};
#pragma unroll
    for (int e = 0; e < 8; ++e) {
      uint32_t h = f2bf(vv[e]);
      a_hi[kk][e] = (short)(ushort)h;
      a_lo[kk][e] = (short)(ushort)f2bf(vv[e] - bf2f(h));
      xnpart = fmaf(vv[e], vv[e], xnpart);
    }
  }
  // row-norm: combine the 4 k-groups; every lane then holds row (l&15)'s norm
  xnpart += __shfl_xor(xnpart, 16, 64);
  xnpart += __shfl_xor(xnpart, 32, 64);
  float xnr[4];
#pragma unroll
  for (int r = 0; r < 4; ++r) xnr[r] = __shfl(xnpart, kgrp * 4 + r, 64);

  float b1[2][4], b2[2][4];
  int k1[2][4];
#pragma unroll
  for (int s = 0; s < 2; ++s)
#pragma unroll
    for (int r = 0; r < 4; ++r) { b1[s][r] = -1e30f; b2[s][r] = -1e30f; k1[s][r] = 0; }

  for (int ct = 0; ct < 32; ++ct) {
    __syncthreads();
    {
      const uint4* gh = (const uint4*)(cbhi + (size_t)ct * 32 * DIM);
      const uint4* gl = (const uint4*)(cblo + (size_t)ct * 32 * DIM);
#pragma unroll
      for (int q = 0; q < 2; ++q) {
        int li = tid + q * 256;        // 0..511
        int row = li >> 4, c8 = li & 15;
        *(uint4*)(csh + row * 136 + c8 * 8) = gh[li];
        *(uint4*)(csl + row * 136 + c8 * 8) = gl[li];
      }
      if (tid < 32) cn_s[tid] = cnf[ct * 32 + tid];
    }
    __syncthreads();

    f32x4 acc0 = {0.f, 0.f, 0.f, 0.f}, acc1 = {0.f, 0.f, 0.f, 0.f};
#pragma unroll
    for (int kk = 0; kk < 4; ++kk) {
      int off = kk * 32 + kgrp * 8;
      short8 bh0 = *(const short8*)(csh + colc * 136 + off);
      short8 bl0 = *(const short8*)(csl + colc * 136 + off);
      short8 bh1 = *(const short8*)(csh + (colc + 16) * 136 + off);
      short8 bl1 = *(const short8*)(csl + (colc + 16) * 136 + off);
      acc0 = __builtin_amdgcn_mfma_f32_16x16x32_bf16(a_lo[kk], bh0, acc0, 0, 0, 0);
      acc1 = __builtin_amdgcn_mfma_f32_16x16x32_bf16(a_lo[kk], bh1, acc1, 0, 0, 0);
      acc0 = __builtin_amdgcn_mfma_f32_16x16x32_bf16(a_hi[kk], bl0, acc0, 0, 0, 0);
      acc1 = __builtin_amdgcn_mfma_f32_16x16x32_bf16(a_hi[kk], bl1, acc1, 0, 0, 0);
      acc0 = __builtin_amdgcn_mfma_f32_16x16x32_bf16(a_hi[kk], bh0, acc0, 0, 0, 0);
      acc1 = __builtin_amdgcn_mfma_f32_16x16x32_bf16(a_hi[kk], bh1, acc1, 0, 0, 0);
    }

#pragma unroll
    for (int sub = 0; sub < 2; ++sub) {
      f32x4 A = sub ? acc1 : acc0;
      int code_l = sub * 16 + colc;
      float cn = cn_s[code_l];
      int code_g = ct * 32 + code_l;
#pragma unroll
      for (int r = 0; r < 4; ++r) {
        int row_g = blk * 64 + wid * 16 + kgrp * 4 + r;
        uint32_t j = ((uint32_t)row_g << 10) + (uint32_t)code_g;
        float g = gumb_fast(tf_xor(j));
        float d2 = (xnr[r] + cn) - 2.0f * A[r];
        float z = g - sqrtf(fmaxf(d2, 1e-12f));
        if (z > b1[sub][r]) { b2[sub][r] = b1[sub][r]; b1[sub][r] = z; k1[sub][r] = code_g; }
        else if (z > b2[sub][r]) b2[sub][r] = z;
      }
    }
  }

  // merge sub0/sub1, then reduce across the 16 col-class lanes
  float m1[4], m2[4];
  int mk[4];
#pragma unroll
  for (int r = 0; r < 4; ++r) {
    if (b1[1][r] > b1[0][r] || (b1[1][r] == b1[0][r] && k1[1][r] < k1[0][r])) {
      m1[r] = b1[1][r]; mk[r] = k1[1][r]; m2[r] = fmaxf(b1[0][r], b2[1][r]);
    } else {
      m1[r] = b1[0][r]; mk[r] = k1[0][r]; m2[r] = fmaxf(b1[1][r], b2[0][r]);
    }
  }
#pragma unroll
  for (int off = 8; off >= 1; off >>= 1) {
#pragma unroll
    for (int r = 0; r < 4; ++r) {
      float o1 = __shfl_down(m1[r], off, 16);
      int ok = __shfl_down(mk[r], off, 16);
      float o2 = __shfl_down(m2[r], off, 16);
      if (o1 > m1[r] || (o1 == m1[r] && ok < mk[r])) {
        m2[r] = fmaxf(m1[r], o2); m1[r] = o1; mk[r] = ok;
      } else {
        m2[r] = fmaxf(m2[r], o1);
      }
    }
  }
  if (colc == 0) {
#pragma unroll
    for (int r = 0; r < 4; ++r) {
      int row_g = blk * 64 + wid * 16 + kgrp * 4 + r;
      out_idx[row_g] = (uint32_t)mk[r];
      if (m1[r] - m2[r] < MARGIN) {
        uint32_t pos = atomicAdd(fix_count, 1u);
        if (pos < NTOK) fix_list[pos] = row_g;
      }
    }
  }
}

// ---------- fixup: re-decide flagged rows with r8-identical arithmetic -----
__global__ __launch_bounds__(256)
void vq_fixup(const float* __restrict__ x, const float* __restrict__ cb,
              const double* __restrict__ cnorm, const uint32_t* __restrict__ fix_count,
              const uint32_t* __restrict__ fix_list, uint32_t* __restrict__ out_idx) {
  __shared__ float xrow[DIM];
  __shared__ double xn_sh;
  __shared__ double bz_sh[256];
  __shared__ int bk_sh[256];

  const int t = threadIdx.x;  // 256
  const uint32_t cnt = fix_count[0];

  for (uint32_t e = blockIdx.x; e < cnt && e < NTOK; e += gridDim.x) {
    const uint32_t row = fix_list[e];
    if (t < 32) ((float4*)xrow)[t] = ((const float4*)(x + (size_t)row * DIM))[t];
    __syncthreads();
    if (t == 0) {
      double s = 0.0;
#pragma unroll
      for (int d = 0; d < DIM; ++d) s = fma((double)xrow[d], (double)xrow[d], s);
      xn_sh = s;
    }
    __syncthreads();
    const double xn = xn_sh;
    const uint32_t jb = row << 10;

    double bz = -1e300;
    int bk = 0;
#pragma unroll
    for (int q = 0; q < 4; ++q) {
      const int kg = t + q * 256;
      float acc = 0.0f;
      const float* crow = cb + (size_t)kg * DIM;
#pragma unroll
      for (int d = 0; d < DIM; ++d) acc = fmaf(xrow[d], crow[d], acc);
      float g = gumb32(tf_xor(jb + (uint32_t)kg));
      double d2 = (xn + cnorm[kg]) - 2.0 * (double)acc;
      double dist = sqrt(fmax(d2, 1e-12));
      double z = (double)g - dist;
      if (z > bz) { bz = z; bk = kg; }
    }
    bz_sh[t] = bz; bk_sh[t] = bk;
    __syncthreads();
    for (int s = 128; s >= 1; s >>= 1) {
      if (t < s) {
        double ov = bz_sh[t + s]; int ok = bk_sh[t + s];
        if (ov > bz_sh[t] || (ov == bz_sh[t] && ok < bk_sh[t])) {
          bz_sh[t] = ov; bk_sh[t] = ok;
        }
      }
      __syncthreads();
    }
    if (t == 0) out_idx[row] = (uint32_t)bk_sh[0];
    __syncthreads();
  }
}

// ---------- per-row finish: one wave per row, coalesced one-hot stores -----
__global__ __launch_bounds__(256)
void vq_finish(const float* __restrict__ x, const float* __restrict__ cb,
               const uint32_t* __restrict__ idx, float* __restrict__ codes,
               float* __restrict__ ncb, float* __restrict__ lpart) {
  const int lane = threadIdx.x & 63;
  const int wid = threadIdx.x >> 6;

  for (int r = blockIdx.x * 4 + wid; r < NTOK; r += 8192) {
    const int k = (int)idx[r];
    float2 xv = ((const float2*)(x + (size_t)r * DIM))[lane];
    float2 cv = ((const float2*)(cb + (size_t)k * DIM))[lane];
    float dx = cv.x - xv.x, dy = cv.y - xv.y;
    float s = dx * dx + dy * dy;
#pragma unroll
    for (int off = 32; off >= 1; off >>= 1) s += __shfl_down(s, off, 64);

    atomicAdd(ncb + k * DIM + 2 * lane,     0.01f * xv.x);
    atomicAdd(ncb + k * DIM + 2 * lane + 1, 0.01f * xv.y);

    float4* crow = (float4*)(codes + (size_t)r * KC);
#pragma unroll
    for (int q = 0; q < 4; ++q) {
      int c4 = q * 64 + lane;          // contiguous 1KB per store instruction
      float4 v = make_float4(0.f, 0.f, 0.f, 0.f);
      int dlt = k - c4 * 4;
      if (dlt >= 0 && dlt < 4) ((float*)&v)[dlt] = 1.0f;
      crow[c4] = v;
    }
    if (lane == 0) atomicAdd(lpart + (r & 1023), s);
  }
}

// ---------- loss = 1.25 * sum / (N*D) ----------
__global__ void vq_loss_final(const float* __restrict__ lpart, float* __restrict__ loss) {
  const int t = threadIdx.x;  // 256
  float s = 0.0f;
#pragma unroll
  for (int q = 0; q < 4; ++q) s += lpart[t + q * 256];
#pragma unroll
  for (int off = 32; off >= 1; off >>= 1) s += __shfl_down(s, off, 64);
  __shared__ float sw[4];
  if ((t & 63) == 0) sw[t >> 6] = s;
  __syncthreads();
  if (t == 0) {
    float total = (sw[0] + sw[1]) + (sw[2] + sw[3]);
    loss[0] = 1.25f * (total / 8388608.0f);
  }
}

extern "C" void kernel_launch(void* const* d_in, const int* in_sizes, int n_in,
                              void* d_out, int out_size, void* d_ws, size_t ws_size,
                              hipStream_t stream) {
  const float* x  = (const float*)d_in[0];   // (N, D) fp32
  const float* cb = (const float*)d_in[1];   // (K, D) fp32

  float* codes = (float*)d_out;                           // N*K f32
  float* loss  = (float*)d_out + (size_t)NTOK * KC;       // 1
  float* ncb   = loss + 1;                                // K*D

  uint32_t* idx       = (uint32_t*)d_ws;                          // 256 KB
  double*   cnorm     = (double*)(idx + NTOK);                    // 8 KB
  float*    cnf       = (float*)(cnorm + KC);                     // 4 KB
  float*    lpart     = cnf + KC;                                 // 4 KB
  uint32_t* fix_count = (uint32_t*)(lpart + KC);                  // 256 B
  uint32_t* fix_list  = fix_count + 64;                           // 256 KB
  ushort*   cbhi      = (ushort*)(fix_list + NTOK);               // 256 KB
  ushort*   cblo      = cbhi + (size_t)KC * DIM;                  // 256 KB

  vq_cnorm_ema<<<KC, 64, 0, stream>>>(cb, cnorm, cnf, cbhi, cblo, lpart, fix_count, ncb);
  vq_main<<<1024, 256, 0, stream>>>(x, cbhi, cblo, cnf, idx, fix_count, fix_list);
  vq_fixup<<<256, 256, 0, stream>>>(x, cb, cnorm, fix_count, fix_list, idx);
  vq_finish<<<2048, 256, 0, stream>>>(x, cb, idx, codes, ncb, lpart);
  vq_loss_final<<<1, 256, 0, stream>>>(lpart, loss);
}